// Round 12
// baseline (875.652 us; speedup 1.0000x reference)
//
#include <hip/hip_runtime.h>
#include <stdint.h>

#define NTOK 4096
#define DDIM 2048
#define FDIM 5632
#define NEXP 8
#define RLORA 16
#define TWOF 11264
#define BCOLS 11520   // 2F + 2*E*R  (w1 | w3 | a1 | a3 rows)
#define PADROWS 10240 // 8192 pairs + worst-case 8*255 padding, 256-granular
#define LSCALE 2.0f

typedef __attribute__((ext_vector_type(4))) float f32x4;
typedef __attribute__((ext_vector_type(8))) short short8;
typedef unsigned short u16;

#define AS1 __attribute__((address_space(1)))
#define AS3 __attribute__((address_space(3)))

__device__ __forceinline__ float b2f(short s) {
  union { float f; unsigned u; } v;
  v.u = ((unsigned)(u16)s) << 16;
  return v.f;
}
__device__ __forceinline__ u16 f2b(float f) {
  union { float f; unsigned u; } v; v.f = f;
  unsigned r = v.u + 0x7fffu + ((v.u >> 16) & 1u);   // RNE bf16
  return (u16)(r >> 16);
}

// ---------------- cast f32 -> bf16, 4-wide (w2) ----------------
__global__ __launch_bounds__(256) void cast_kernel(const float* __restrict__ src, u16* __restrict__ dst, int n4) {
  int stride = gridDim.x * 256;
  for (int i = blockIdx.x * 256 + threadIdx.x; i < n4; i += stride) {
    float4 v = reinterpret_cast<const float4*>(src)[i];
    ushort4 o;
    o.x = f2b(v.x); o.y = f2b(v.y); o.z = f2b(v.z); o.w = f2b(v.w);
    reinterpret_cast<ushort4*>(dst)[i] = o;
  }
}

// ------------- merged cast: Ball = [w1; w3; a1; a3] rows, f32 -> bf16 -------------
__global__ __launch_bounds__(256) void cast_ball(const float* __restrict__ w1, const float* __restrict__ w3,
                                                 const float* __restrict__ a1, const float* __restrict__ a3,
                                                 u16* __restrict__ Ball) {
  const int n4 = BCOLS * DDIM / 4;
  int stride = gridDim.x * 256;
  for (int i = blockIdx.x * 256 + threadIdx.x; i < n4; i += stride) {
    int row = i >> 9;            // DDIM/4 = 512
    int c4 = i & 511;
    const float* src;
    if (row < FDIM)            src = w1 + (size_t)row * DDIM;
    else if (row < TWOF)       src = w3 + (size_t)(row - FDIM) * DDIM;
    else if (row < TWOF + 128) src = a1 + (size_t)(row - TWOF) * DDIM;
    else                       src = a3 + (size_t)(row - TWOF - 128) * DDIM;
    float4 v = reinterpret_cast<const float4*>(src)[c4];
    ushort4 o;
    o.x = f2b(v.x); o.y = f2b(v.y); o.z = f2b(v.z); o.w = f2b(v.w);
    reinterpret_cast<ushort4*>(Ball)[i] = o;
  }
}

// ------------- router + x-cast fused: logits top-2 softmax, and xb write -------------
__global__ __launch_bounds__(256) void router_cast(const float* __restrict__ x, const float* __restrict__ gw,
                                                   int2* __restrict__ tok_e, float2* __restrict__ tok_w,
                                                   u16* __restrict__ xb) {
  int tok = blockIdx.x;
  const float* xr = x + (size_t)tok * DDIM;
  int j0 = threadIdx.x * 8;    // 256 threads x 8 = 2048
  float4 v0 = *reinterpret_cast<const float4*>(xr + j0);
  float4 v1 = *reinterpret_cast<const float4*>(xr + j0 + 4);
  float v[8] = {v0.x, v0.y, v0.z, v0.w, v1.x, v1.y, v1.z, v1.w};
  short8 ob;
#pragma unroll
  for (int j = 0; j < 8; ++j) ob[j] = (short)f2b(v[j]);
  *reinterpret_cast<short8*>(xb + (size_t)tok * DDIM + j0) = ob;
  float acc[NEXP];
#pragma unroll
  for (int e = 0; e < NEXP; ++e) {
    const float* gr = gw + e * DDIM + j0;
    float s = 0.f;
#pragma unroll
    for (int j = 0; j < 8; ++j) s += v[j] * gr[j];
    acc[e] = s;
  }
#pragma unroll
  for (int e = 0; e < NEXP; ++e) {
#pragma unroll
    for (int off = 32; off > 0; off >>= 1) acc[e] += __shfl_down(acc[e], off);
  }
  __shared__ float red[4][NEXP];
  int wid = threadIdx.x >> 6;
  int lane = threadIdx.x & 63;
  if (lane == 0) {
#pragma unroll
    for (int e = 0; e < NEXP; ++e) red[wid][e] = acc[e];
  }
  __syncthreads();
  if (threadIdx.x == 0) {
    float l[NEXP];
#pragma unroll
    for (int e = 0; e < NEXP; ++e) l[e] = red[0][e] + red[1][e] + red[2][e] + red[3][e];
    int i0 = 0;
#pragma unroll
    for (int e = 1; e < NEXP; ++e) if (l[e] > l[i0]) i0 = e;   // strict >: first max (top_k tie rule)
    int i1 = (i0 == 0) ? 1 : 0;
#pragma unroll
    for (int e = 0; e < NEXP; ++e) if (e != i0 && e != i1 && l[e] > l[i1]) i1 = e;
    float ex = __expf(l[i1] - l[i0]);       // <= 1
    float w0 = 1.f / (1.f + ex);
    float w1v = ex / (1.f + ex);
    int2 ev; ev.x = i0; ev.y = i1;
    float2 wv; wv.x = w0; wv.y = w1v;
    tok_e[tok] = ev;
    tok_w[tok] = wv;
  }
}

// ---------------- bucket (token,slot) pairs by expert, 256-padded ----------------
__global__ __launch_bounds__(256) void build_pairs(const int2* __restrict__ tok_e,
                                                   int* __restrict__ pair_tok,
                                                   int* __restrict__ pair_k, int* __restrict__ poff) {
  __shared__ int cnt[NEXP];
  __shared__ int base[NEXP + 1];
  __shared__ int cur[NEXP];
  if (threadIdx.x < NEXP) cnt[threadIdx.x] = 0;
  __syncthreads();
  for (int t = threadIdx.x; t < NTOK; t += 256) {
    int2 ee = tok_e[t];
    atomicAdd(&cnt[ee.x], 1);
    atomicAdd(&cnt[ee.y], 1);
  }
  for (int i = threadIdx.x; i < PADROWS; i += 256) pair_tok[i] = -1;
  __syncthreads();
  if (threadIdx.x == 0) {
    int o = 0;
#pragma unroll
    for (int e = 0; e < NEXP; ++e) { base[e] = o; o += ((cnt[e] + 255) >> 8) << 8; }
    base[NEXP] = o;
  }
  __syncthreads();
  if (threadIdx.x < NEXP) cur[threadIdx.x] = base[threadIdx.x];
  __syncthreads();
  for (int t = threadIdx.x; t < NTOK; t += 256) {
    int2 ee = tok_e[t];
    int s0 = atomicAdd(&cur[ee.x], 1);
    pair_tok[s0] = t; pair_k[s0] = 0;
    int s1 = atomicAdd(&cur[ee.y], 1);
    pair_tok[s1] = t; pair_k[s1] = 1;
  }
  __syncthreads();
  if (threadIdx.x <= NEXP) poff[threadIdx.x] = base[threadIdx.x];
}

// ====== 256x128 bf16 MFMA GEMM core: BK=64, single-buffer, 512 thr / 8 waves ======
// C = A(rm [M][K]) * B(rm [N][K])^T. 8 waves as 4M x 2N, per-wave 64x64 = acc[4][4]
// (64 acc VGPR -> fits the (512,4) 128-VGPR budget). LDS: A 256x64 (32KB) +
// B 128x64 (16KB) = 48KB single-buffer, 2 blocks/CU = 16 waves.
// Rationale (r12): staging bytes per MFMA drops 4 -> 5.33 MFMA/KB vs 128x128 —
// the measured per-step wall (8380cy for 512 MFMA at 128^2) is dominated by the
// L2 staging term; bigger tile AREA is the only lever that reduces it at fixed
// schedule. Swizzle identical to r10's verified 0-conflict geometry.
__device__ __forceinline__ void mm256x128(const u16* __restrict__ A, const u16* __restrict__ B,
                                          int lda, int ldb, int NT,
                                          char* lA, char* lB, int tid,
                                          int rowAb, int rowBb, int col0,
                                          f32x4 (&acc)[4][4]) {
  for (int t = 0; t < NT; ++t) {
    __syncthreads();                          // all waves done reading previous K-step
#pragma unroll
    for (int h = 0; h < 4; ++h) {             // A: 2048 16B chunks, 4/thread
      int q = h * 512 + tid, r = q >> 3, g = q & 7, gs = g ^ (r & 7);
      const char* s = (const char*)(A + (size_t)t * 64 + (size_t)r * lda) + gs * 16;
      __builtin_amdgcn_global_load_lds((const AS1 void*)s, (AS3 void*)(lA + q * 16), 16, 0, 0);
    }
#pragma unroll
    for (int h = 0; h < 2; ++h) {             // B: 1024 16B chunks, 2/thread
      int q = h * 512 + tid, r = q >> 3, g = q & 7, gs = g ^ (r & 7);
      const char* s = (const char*)(B + (size_t)t * 64 + (size_t)r * ldb) + gs * 16;
      __builtin_amdgcn_global_load_lds((const AS1 void*)s, (AS3 void*)(lB + q * 16), 16, 0, 0);
    }
    __syncthreads();                          // implicit vmcnt(0): tile landed
    short8 av[4], bv[4];
#pragma unroll
    for (int kh = 0; kh < 2; ++kh) {
      int col = col0 ^ (kh << 6);
#pragma unroll
      for (int i = 0; i < 4; ++i) {
        av[i] = *(const short8*)(lA + rowAb + i * 2048 + col);
        bv[i] = *(const short8*)(lB + rowBb + i * 2048 + col);
      }
#pragma unroll
      for (int i = 0; i < 4; ++i)
#pragma unroll
        for (int j = 0; j < 4; ++j)
          acc[i][j] = __builtin_amdgcn_mfma_f32_16x16x32_bf16(av[i], bv[j], acc[i][j], 0, 0, 0);
    }
  }
}

// ---------------- GEMM1: base13_ext = x_bf16 @ [w1;w3;a1;a3]^T ----------------
// 1440 blocks = 16 mi (256-row) x 90 nt (128-col); XCD-chunked 180/XCD.
__global__ __launch_bounds__(512, 4) void gemm_base(const u16* __restrict__ xb, const u16* __restrict__ Ball,
                                                    u16* __restrict__ base13) {
  __shared__ char lA[32768];
  __shared__ char lB[16384];
  const int tid = threadIdx.x;
  const int lane = tid & 63, wid = tid >> 6;
  const int wr = wid >> 1, wc = wid & 1;
  const int lm = lane & 15, lg = lane >> 4;
  const int col0 = (lg << 4) ^ ((lm & 7) << 4);
  const int rowAb = (wr * 64 + lm) * 128;
  const int rowBb = (wc * 64 + lm) * 128;
  const int lq = (lane >> 4) << 2;
  int orig = blockIdx.x;
  int wgid = (orig & 7) * 180 + (orig >> 3);
  int mi = wgid % 16, nt = wgid / 16;
  int m0 = mi << 8, n0 = nt << 7;
  f32x4 acc[4][4];
  f32x4 z = {0.f, 0.f, 0.f, 0.f};
#pragma unroll
  for (int i = 0; i < 4; ++i)
#pragma unroll
    for (int j = 0; j < 4; ++j) acc[i][j] = z;
  mm256x128(xb + (size_t)m0 * DDIM, Ball + (size_t)n0 * DDIM, DDIM, DDIM, DDIM / 64,
            lA, lB, tid, rowAb, rowBb, col0, acc);
#pragma unroll
  for (int i = 0; i < 4; ++i) {
#pragma unroll
    for (int n = 0; n < 4; ++n) {
      int col = n0 + wc * 64 + n * 16 + lm;
#pragma unroll
      for (int q = 0; q < 4; ++q) {
        int row = m0 + wr * 64 + i * 16 + lq + q;
        base13[(size_t)row * BCOLS + col] = f2b(acc[i][n][q]);
      }
    }
  }
}

// ---------------- act: SwiGLU with rank-16 LoRA on h1/h3 ----------------
// (r11-verified slot-rotation swizzle: conflicts 1.6e8 -> ~0)
__global__ __launch_bounds__(256) void act_kernel(const u16* __restrict__ base13,
                                                  const float* __restrict__ b1, const float* __restrict__ b3,
                                                  const int* __restrict__ pair_tok, const int* __restrict__ poff,
                                                  u16* __restrict__ act) {
  __shared__ float lb1[128 * 16];
  __shared__ float lb3[128 * 16];
  int f0 = blockIdx.x * 128;
  int r0 = blockIdx.y * 32;
  if (r0 >= poff[NEXP]) return;
  int e = 0;
  while (r0 >= poff[e + 1]) ++e;
  const float4* pb1 = reinterpret_cast<const float4*>(b1 + ((size_t)e * FDIM + f0) * RLORA);
  const float4* pb3 = reinterpret_cast<const float4*>(b3 + ((size_t)e * FDIM + f0) * RLORA);
  for (int i = threadIdx.x; i < 128 * 16 / 4; i += 256) {
    int r = i >> 2, c = i & 3;
    int cs = (c + (r >> 5)) & 3;             // rotated slot
    *reinterpret_cast<float4*>(lb1 + r * 16 + cs * 4) = pb1[i];
    *reinterpret_cast<float4*>(lb3 + r * 16 + cs * 4) = pb3[i];
  }
  __syncthreads();
  int pr = r0 + (threadIdx.x >> 3);
  int fg = (threadIdx.x & 7) << 4;
  int tok = pair_tok[pr];
  if (tok < 0) return;
  const u16* bp = base13 + (size_t)tok * BCOLS;
  short8 x1a = *(const short8*)(bp + TWOF + e * 16);
  short8 x1b = *(const short8*)(bp + TWOF + e * 16 + 8);
  short8 x3a = *(const short8*)(bp + TWOF + NEXP * RLORA + e * 16);
  short8 x3b = *(const short8*)(bp + TWOF + NEXP * RLORA + e * 16 + 8);
  float xa1[16], xa3[16];
#pragma unroll
  for (int r = 0; r < 8; ++r) {
    xa1[r] = b2f(x1a[r]); xa1[r + 8] = b2f(x1b[r]);
    xa3[r] = b2f(x3a[r]); xa3[r + 8] = b2f(x3b[r]);
  }
  short8 h1a = *(const short8*)(bp + f0 + fg);
  short8 h1b = *(const short8*)(bp + f0 + fg + 8);
  short8 h3a = *(const short8*)(bp + FDIM + f0 + fg);
  short8 h3b = *(const short8*)(bp + FDIM + f0 + fg + 8);
  short8 o0, o1;
#pragma unroll
  for (int ii = 0; ii < 16; ++ii) {
    float hb1 = b2f(ii < 8 ? h1a[ii] : h1b[ii - 8]);
    float hb3 = b2f(ii < 8 ? h3a[ii] : h3b[ii - 8]);
    int row = fg + ii;
    int rot = row >> 5;
    const float* l1 = lb1 + row * 16;
    const float* l3 = lb3 + row * 16;
    float d1 = 0.f, d3 = 0.f;
#pragma unroll
    for (int c = 0; c < 4; ++c) {
      int cs = ((c + rot) & 3) << 2;
      float4 v1 = *reinterpret_cast<const float4*>(l1 + cs);
      float4 v3 = *reinterpret_cast<const float4*>(l3 + cs);
      d1 += xa1[4 * c + 0] * v1.x + xa1[4 * c + 1] * v1.y + xa1[4 * c + 2] * v1.z + xa1[4 * c + 3] * v1.w;
      d3 += xa3[4 * c + 0] * v3.x + xa3[4 * c + 1] * v3.y + xa3[4 * c + 2] * v3.z + xa3[4 * c + 3] * v3.w;
    }
    float h1 = hb1 + LSCALE * d1;
    float h3 = hb3 + LSCALE * d3;
    float s = h1 / (1.f + __expf(-h1));
    u16 ob = f2b(s * h3);
    if (ii < 8) o0[ii] = (short)ob; else o1[ii - 8] = (short)ob;
  }
  short8* dst = (short8*)(act + (size_t)pr * FDIM + f0 + fg);
  dst[0] = o0;
  dst[1] = o1;
}

// ---------------- ya2 = act @ a2[e]^T  (rank-16 reduce over F) ----------------
__global__ __launch_bounds__(256) void ya2_kernel(const u16* __restrict__ act, const float* __restrict__ a2,
                                                  const int* __restrict__ poff, float* __restrict__ ya2) {
  __shared__ float lact[16 * 68];
  __shared__ float la2[16 * 68];
  int r0 = blockIdx.x * 16;
  if (r0 >= poff[NEXP]) return;
  int e = 0;
  while (r0 >= poff[e + 1]) ++e;
  int p = threadIdx.x >> 4;
  int r = threadIdx.x & 15;
  int lrow = threadIdx.x >> 4;
  int c4 = (threadIdx.x & 15) << 2;
  float acc = 0.f;
  for (int f0 = 0; f0 < FDIM; f0 += 64) {
    __syncthreads();
    ushort4 av = *reinterpret_cast<const ushort4*>(act + (size_t)(r0 + lrow) * FDIM + f0 + c4);
    lact[lrow * 68 + c4 + 0] = b2f((short)av.x);
    lact[lrow * 68 + c4 + 1] = b2f((short)av.y);
    lact[lrow * 68 + c4 + 2] = b2f((short)av.z);
    lact[lrow * 68 + c4 + 3] = b2f((short)av.w);
    float4 bv = *reinterpret_cast<const float4*>(a2 + ((size_t)e * RLORA + lrow) * FDIM + f0 + c4);
    *reinterpret_cast<float4*>(la2 + lrow * 68 + c4) = bv;
    __syncthreads();
#pragma unroll
    for (int jj = 0; jj < 64; jj += 4) {
      float4 a4 = *reinterpret_cast<const float4*>(lact + p * 68 + jj);
      float4 b4 = *reinterpret_cast<const float4*>(la2 + r * 68 + jj);
      acc += a4.x * b4.x + a4.y * b4.y + a4.z * b4.z + a4.w * b4.w;
    }
  }
  ya2[(size_t)(r0 + p) * RLORA + r] = acc;
}

// -------- grouped down GEMM, 256x128 tile-per-block + LoRA epilogue --------
// Grid 640 = 40 mtiles (256-row) x 16 nt. Per XCD: 80 wgids = 5 mloc x 16 nt;
// mi = mloc*8 + xcd spreads dead mtiles across XCDs; the 16 nt of one mi are
// consecutive (A panel 2.88 MB L2-hot). Live blocks ~528 <= 512 CU-slots x ~1 round.
__global__ __launch_bounds__(512, 4) void gemm_down(const u16* __restrict__ act, const u16* __restrict__ w2b,
                                                    const float* __restrict__ b2, const float* __restrict__ ya2,
                                                    const int* __restrict__ pair_tok, const int* __restrict__ pair_k,
                                                    const int* __restrict__ poff,
                                                    float* __restrict__ slots) {
  int orig = blockIdx.x;
  int xcd = orig & 7;
  int l = orig >> 3;                          // 0..79
  int nt = l & 15;
  int mi = (l >> 4) * 8 + xcd;                // 0..39, dead spread across XCDs
  int m0 = mi << 8;
  if (m0 >= poff[NEXP]) return;
  int e = 0;
  while (m0 >= poff[e + 1]) ++e;              // 256-granular padding: tile within one expert
  int n0 = nt << 7;
  __shared__ char lA[32768];
  __shared__ char lB[16384];
  const int tid = threadIdx.x;
  const int lane = tid & 63, wid = tid >> 6;
  const int wr = wid >> 1, wc = wid & 1;
  const int lm = lane & 15, lg = lane >> 4;
  const int col0 = (lg << 4) ^ ((lm & 7) << 4);
  const int rowAb = (wr * 64 + lm) * 128;
  const int rowBb = (wc * 64 + lm) * 128;
  const int lq = (lane >> 4) << 2;
  f32x4 acc[4][4];
  f32x4 z = {0.f, 0.f, 0.f, 0.f};
#pragma unroll
  for (int i = 0; i < 4; ++i)
#pragma unroll
    for (int j = 0; j < 4; ++j) acc[i][j] = z;
  mm256x128(act + (size_t)m0 * FDIM, w2b + (size_t)n0 * FDIM, FDIM, FDIM, FDIM / 64,
            lA, lB, tid, rowAb, rowBb, col0, acc);
#pragma unroll
  for (int n = 0; n < 4; ++n) {
    int col = n0 + wc * 64 + n * 16 + lm;
    const float* b2p = b2 + ((size_t)e * DDIM + col) * RLORA;
    float b2v[16];
#pragma unroll
    for (int rr = 0; rr < 16; ++rr) b2v[rr] = b2p[rr];
#pragma unroll
    for (int i = 0; i < 4; ++i) {
#pragma unroll
      for (int q = 0; q < 4; ++q) {
        int pidx = m0 + wr * 64 + i * 16 + lq + q;
        int tok = pair_tok[pidx];
        if (tok < 0) continue;
        const float* yr = ya2 + (size_t)pidx * RLORA;
        float dot = 0.f;
#pragma unroll
        for (int rr = 0; rr < 16; ++rr) dot += yr[rr] * b2v[rr];
        slots[((size_t)tok * 2 + pair_k[pidx]) * DDIM + col] = acc[i][n][q] + LSCALE * dot;
      }
    }
  }
}

// ---------------- combine: out = w0*slot0 + w1*slot1 ----------------
__global__ __launch_bounds__(256) void combine_kernel(const float4* __restrict__ slots,
                                                      const float2* __restrict__ tok_w,
                                                      float4* __restrict__ out) {
  const int n4 = NTOK * (DDIM / 4);
  int stride = gridDim.x * 256;
  for (int i = blockIdx.x * 256 + threadIdx.x; i < n4; i += stride) {
    int tok = i >> 9;          // DDIM/4 = 512
    int c = i & 511;
    float2 w = tok_w[tok];
    float4 v0 = slots[(size_t)(tok * 2) * 512 + c];
    float4 v1 = slots[(size_t)(tok * 2 + 1) * 512 + c];
    float4 o;
    o.x = w.x * v0.x + w.y * v1.x;
    o.y = w.x * v0.y + w.y * v1.y;
    o.z = w.x * v0.z + w.y * v1.z;
    o.w = w.x * v0.w + w.y * v1.w;
    out[i] = o;
  }
}

extern "C" void kernel_launch(void* const* d_in, const int* in_sizes, int n_in,
                              void* d_out, int out_size, void* d_ws, size_t ws_size,
                              hipStream_t stream) {
  (void)in_sizes; (void)n_in; (void)out_size; (void)ws_size;
  const float* x  = (const float*)d_in[0];
  const float* gw = (const float*)d_in[1];
  const float* w1 = (const float*)d_in[2];
  const float* w3 = (const float*)d_in[3];
  const float* w2 = (const float*)d_in[4];
  const float* a1 = (const float*)d_in[5];
  const float* b1 = (const float*)d_in[6];
  const float* a3 = (const float*)d_in[7];
  const float* b3 = (const float*)d_in[8];
  const float* a2 = (const float*)d_in[9];
  const float* b2 = (const float*)d_in[10];
  float* out = (float*)d_out;

  char* ws = (char*)d_ws;
  size_t off = 0;
  auto take = [&](size_t bytes) -> char* {
    char* p = ws + off;
    off += (bytes + 255) & ~(size_t)255;
    return p;
  };
  // region 1: base13 (94.4 MB) -> later reused by slots (67.1) + ya2 (0.66)
  char* reg1 = take((size_t)NTOK * BCOLS * 2);
  u16* base13 = (u16*)reg1;
  float* slots = (float*)reg1;
  float* ya2 = (float*)(reg1 + (size_t)NTOK * 2 * DDIM * 4);
  // region 2: act (115.3 MB); xb (16.8) + Ball (47.2) overlap its head (dead after gemm_base)
  char* reg2 = take((size_t)PADROWS * FDIM * 2);
  u16* actb = (u16*)reg2;
  u16* xb = (u16*)reg2;
  u16* Ball = (u16*)(reg2 + (size_t)NTOK * DDIM * 2);
  // region 3: w2b + small arrays
  u16* w2b = (u16*)take((size_t)DDIM * FDIM * 2);
  int2* tok_e   = (int2*)take((size_t)NTOK * 8);
  float2* tok_w = (float2*)take((size_t)NTOK * 8);
  int* pair_tok = (int*)take((size_t)PADROWS * 4);
  int* pair_k   = (int*)take((size_t)PADROWS * 4);
  int* poff     = (int*)take(256);

  cast_ball<<<2048, 256, 0, stream>>>(w1, w3, a1, a3, Ball);
  cast_kernel<<<1024, 256, 0, stream>>>(w2, w2b, DDIM * FDIM / 4);
  router_cast<<<NTOK, 256, 0, stream>>>(x, gw, tok_e, tok_w, xb);
  build_pairs<<<1, 256, 0, stream>>>(tok_e, pair_tok, pair_k, poff);
  gemm_base<<<1440, 512, 0, stream>>>(xb, Ball, base13);
  dim3 g3(FDIM / 128, PADROWS / 32);
  act_kernel<<<g3, 256, 0, stream>>>(base13, b1, b3, pair_tok, poff, actb);
  ya2_kernel<<<PADROWS / 16, 256, 0, stream>>>(actb, a2, poff, ya2);
  gemm_down<<<640, 512, 0, stream>>>(actb, w2b, b2, ya2, pair_tok, pair_k, poff, slots);
  combine_kernel<<<2048, 256, 0, stream>>>((const float4*)slots, tok_w, (float4*)out);
}

// Round 13
// 775.956 us; speedup vs baseline: 1.1285x; 1.1285x over previous
//
#include <hip/hip_runtime.h>
#include <stdint.h>

#define NTOK 4096
#define DDIM 2048
#define FDIM 5632
#define NEXP 8
#define RLORA 16
#define TWOF 11264
#define BCOLS 11520   // 2F + 2*E*R  (w1 | w3 | a1 | a3 rows)
#define PADROWS 10240 // 8192 pairs + worst-case 8*255 padding, 256-granular
#define LSCALE 2.0f

typedef __attribute__((ext_vector_type(4))) float f32x4;
typedef __attribute__((ext_vector_type(8))) short short8;
typedef unsigned short u16;

#define AS1 __attribute__((address_space(1)))
#define AS3 __attribute__((address_space(3)))

__device__ __forceinline__ float b2f(short s) {
  union { float f; unsigned u; } v;
  v.u = ((unsigned)(u16)s) << 16;
  return v.f;
}
__device__ __forceinline__ u16 f2b(float f) {
  union { float f; unsigned u; } v; v.f = f;
  unsigned r = v.u + 0x7fffu + ((v.u >> 16) & 1u);   // RNE bf16
  return (u16)(r >> 16);
}

// ---------------- cast f32 -> bf16, 4-wide (w2, a2) ----------------
__global__ __launch_bounds__(256) void cast_kernel(const float* __restrict__ src, u16* __restrict__ dst, int n4) {
  int stride = gridDim.x * 256;
  for (int i = blockIdx.x * 256 + threadIdx.x; i < n4; i += stride) {
    float4 v = reinterpret_cast<const float4*>(src)[i];
    ushort4 o;
    o.x = f2b(v.x); o.y = f2b(v.y); o.z = f2b(v.z); o.w = f2b(v.w);
    reinterpret_cast<ushort4*>(dst)[i] = o;
  }
}

// ------------- merged cast: Ball = [w1; w3; a1; a3] rows, f32 -> bf16 -------------
__global__ __launch_bounds__(256) void cast_ball(const float* __restrict__ w1, const float* __restrict__ w3,
                                                 const float* __restrict__ a1, const float* __restrict__ a3,
                                                 u16* __restrict__ Ball) {
  const int n4 = BCOLS * DDIM / 4;
  int stride = gridDim.x * 256;
  for (int i = blockIdx.x * 256 + threadIdx.x; i < n4; i += stride) {
    int row = i >> 9;            // DDIM/4 = 512
    int c4 = i & 511;
    const float* src;
    if (row < FDIM)            src = w1 + (size_t)row * DDIM;
    else if (row < TWOF)       src = w3 + (size_t)(row - FDIM) * DDIM;
    else if (row < TWOF + 128) src = a1 + (size_t)(row - TWOF) * DDIM;
    else                       src = a3 + (size_t)(row - TWOF - 128) * DDIM;
    float4 v = reinterpret_cast<const float4*>(src)[c4];
    ushort4 o;
    o.x = f2b(v.x); o.y = f2b(v.y); o.z = f2b(v.z); o.w = f2b(v.w);
    reinterpret_cast<ushort4*>(Ball)[i] = o;
  }
}

// ------------- router + x-cast fused: logits top-2 softmax, and xb write -------------
__global__ __launch_bounds__(256) void router_cast(const float* __restrict__ x, const float* __restrict__ gw,
                                                   int2* __restrict__ tok_e, float2* __restrict__ tok_w,
                                                   u16* __restrict__ xb) {
  int tok = blockIdx.x;
  const float* xr = x + (size_t)tok * DDIM;
  int j0 = threadIdx.x * 8;    // 256 threads x 8 = 2048
  float4 v0 = *reinterpret_cast<const float4*>(xr + j0);
  float4 v1 = *reinterpret_cast<const float4*>(xr + j0 + 4);
  float v[8] = {v0.x, v0.y, v0.z, v0.w, v1.x, v1.y, v1.z, v1.w};
  short8 ob;
#pragma unroll
  for (int j = 0; j < 8; ++j) ob[j] = (short)f2b(v[j]);
  *reinterpret_cast<short8*>(xb + (size_t)tok * DDIM + j0) = ob;
  float acc[NEXP];
#pragma unroll
  for (int e = 0; e < NEXP; ++e) {
    const float* gr = gw + e * DDIM + j0;
    float s = 0.f;
#pragma unroll
    for (int j = 0; j < 8; ++j) s += v[j] * gr[j];
    acc[e] = s;
  }
#pragma unroll
  for (int e = 0; e < NEXP; ++e) {
#pragma unroll
    for (int off = 32; off > 0; off >>= 1) acc[e] += __shfl_down(acc[e], off);
  }
  __shared__ float red[4][NEXP];
  int wid = threadIdx.x >> 6;
  int lane = threadIdx.x & 63;
  if (lane == 0) {
#pragma unroll
    for (int e = 0; e < NEXP; ++e) red[wid][e] = acc[e];
  }
  __syncthreads();
  if (threadIdx.x == 0) {
    float l[NEXP];
#pragma unroll
    for (int e = 0; e < NEXP; ++e) l[e] = red[0][e] + red[1][e] + red[2][e] + red[3][e];
    int i0 = 0;
#pragma unroll
    for (int e = 1; e < NEXP; ++e) if (l[e] > l[i0]) i0 = e;   // strict >: first max (top_k tie rule)
    int i1 = (i0 == 0) ? 1 : 0;
#pragma unroll
    for (int e = 0; e < NEXP; ++e) if (e != i0 && e != i1 && l[e] > l[i1]) i1 = e;
    float ex = __expf(l[i1] - l[i0]);       // <= 1
    float w0 = 1.f / (1.f + ex);
    float w1v = ex / (1.f + ex);
    int2 ev; ev.x = i0; ev.y = i1;
    float2 wv; wv.x = w0; wv.y = w1v;
    tok_e[tok] = ev;
    tok_w[tok] = wv;
  }
}

// ---------------- bucket (token,slot) pairs by expert, 256-padded ----------------
__global__ __launch_bounds__(256) void build_pairs(const int2* __restrict__ tok_e,
                                                   int* __restrict__ pair_tok,
                                                   int* __restrict__ pair_k, int* __restrict__ poff) {
  __shared__ int cnt[NEXP];
  __shared__ int base[NEXP + 1];
  __shared__ int cur[NEXP];
  if (threadIdx.x < NEXP) cnt[threadIdx.x] = 0;
  __syncthreads();
  for (int t = threadIdx.x; t < NTOK; t += 256) {
    int2 ee = tok_e[t];
    atomicAdd(&cnt[ee.x], 1);
    atomicAdd(&cnt[ee.y], 1);
  }
  for (int i = threadIdx.x; i < PADROWS; i += 256) pair_tok[i] = -1;
  __syncthreads();
  if (threadIdx.x == 0) {
    int o = 0;
#pragma unroll
    for (int e = 0; e < NEXP; ++e) { base[e] = o; o += ((cnt[e] + 255) >> 8) << 8; }
    base[NEXP] = o;
  }
  __syncthreads();
  if (threadIdx.x < NEXP) cur[threadIdx.x] = base[threadIdx.x];
  __syncthreads();
  for (int t = threadIdx.x; t < NTOK; t += 256) {
    int2 ee = tok_e[t];
    int s0 = atomicAdd(&cur[ee.x], 1);
    pair_tok[s0] = t; pair_k[s0] = 0;
    int s1 = atomicAdd(&cur[ee.y], 1);
    pair_tok[s1] = t; pair_k[s1] = 1;
  }
  __syncthreads();
  if (threadIdx.x <= NEXP) poff[threadIdx.x] = base[threadIdx.x];
}

// ======== 128x128 bf16 MFMA GEMM core: BK=64, single-buffer, 4 blocks/CU ========
// (r10/r11-verified best config; r12's 256x128 regressed -> reverted.)
__device__ __forceinline__ void stage64(const u16* __restrict__ src, int ld, char* ldsb, int tid) {
#pragma unroll
  for (int h = 0; h < 4; ++h) {
    int q = h * 256 + tid;            // 0..1023: [128 rows][8 slots]
    int r = q >> 3, g = q & 7;
    int gs = g ^ (r & 7);             // inverse-swizzled source slot
    const char* s = (const char*)(src + (size_t)r * ld) + gs * 16;
    __builtin_amdgcn_global_load_lds((const AS1 void*)s, (AS3 void*)(ldsb + q * 16), 16, 0, 0);
  }
}

__device__ __forceinline__ void mm128(const u16* __restrict__ A, const u16* __restrict__ B,
                                      int lda, int ldb, int NT,
                                      char* lA, char* lB, int tid,
                                      int rowAb, int rowBb, int col0,
                                      f32x4 (&acc)[4][4]) {
  for (int t = 0; t < NT; ++t) {
    __syncthreads();                          // all waves done reading previous K-step
    stage64(A + (size_t)t * 64, lda, lA, tid);
    stage64(B + (size_t)t * 64, ldb, lB, tid);
    __syncthreads();                          // implicit vmcnt(0): tile landed
    short8 av[4], bv[4];
#pragma unroll
    for (int kh = 0; kh < 2; ++kh) {
      int col = col0 ^ (kh << 6);
#pragma unroll
      for (int i = 0; i < 4; ++i) {
        av[i] = *(const short8*)(lA + rowAb + i * 2048 + col);
        bv[i] = *(const short8*)(lB + rowBb + i * 2048 + col);
      }
#pragma unroll
      for (int i = 0; i < 4; ++i)
#pragma unroll
        for (int j = 0; j < 4; ++j)
          acc[i][j] = __builtin_amdgcn_mfma_f32_16x16x32_bf16(av[i], bv[j], acc[i][j], 0, 0, 0);
    }
  }
}

// ---------------- GEMM1: base13_ext = x_bf16 @ [w1;w3;a1;a3]^T ----------------
__global__ __launch_bounds__(256, 4) void gemm_base(const u16* __restrict__ xb, const u16* __restrict__ Ball,
                                                    u16* __restrict__ base13) {
  __shared__ char lA[16384];
  __shared__ char lB[16384];
  const int tid = threadIdx.x;
  const int lane = tid & 63, wid = tid >> 6;
  const int wr = wid >> 1, wc = wid & 1;
  const int lm = lane & 15, lg = lane >> 4;
  const int col0 = (lg << 4) ^ ((lm & 7) << 4);
  const int rowAb = (wr * 64 + lm) * 128;
  const int rowBb = (wc * 64 + lm) * 128;
  const int lq = (lane >> 4) << 2;
  int orig = blockIdx.x;
  int wgid = (orig & 7) * 360 + (orig >> 3);
  int mi = wgid & 31, nt = wgid >> 5;
  int m0 = mi << 7, n0 = nt << 7;
  f32x4 acc[4][4];
  f32x4 z = {0.f, 0.f, 0.f, 0.f};
#pragma unroll
  for (int i = 0; i < 4; ++i)
#pragma unroll
    for (int j = 0; j < 4; ++j) acc[i][j] = z;
  mm128(xb + (size_t)m0 * DDIM, Ball + (size_t)n0 * DDIM, DDIM, DDIM, DDIM / 64,
        lA, lB, tid, rowAb, rowBb, col0, acc);
#pragma unroll
  for (int i = 0; i < 4; ++i) {
#pragma unroll
    for (int n = 0; n < 4; ++n) {
      int col = n0 + wc * 64 + n * 16 + lm;
#pragma unroll
      for (int q = 0; q < 4; ++q) {
        int row = m0 + wr * 64 + i * 16 + lq + q;
        base13[(size_t)row * BCOLS + col] = f2b(acc[i][n][q]);
      }
    }
  }
}

// ---------------- act: SwiGLU with rank-16 LoRA on h1/h3 ----------------
// (r11-verified slot-rotation swizzle: conflicts 1.6e8 -> ~0)
__global__ __launch_bounds__(256) void act_kernel(const u16* __restrict__ base13,
                                                  const float* __restrict__ b1, const float* __restrict__ b3,
                                                  const int* __restrict__ pair_tok, const int* __restrict__ poff,
                                                  u16* __restrict__ act) {
  __shared__ float lb1[128 * 16];
  __shared__ float lb3[128 * 16];
  int f0 = blockIdx.x * 128;
  int r0 = blockIdx.y * 32;
  if (r0 >= poff[NEXP]) return;
  int e = 0;
  while (r0 >= poff[e + 1]) ++e;
  const float4* pb1 = reinterpret_cast<const float4*>(b1 + ((size_t)e * FDIM + f0) * RLORA);
  const float4* pb3 = reinterpret_cast<const float4*>(b3 + ((size_t)e * FDIM + f0) * RLORA);
  for (int i = threadIdx.x; i < 128 * 16 / 4; i += 256) {
    int r = i >> 2, c = i & 3;
    int cs = (c + (r >> 5)) & 3;             // rotated slot
    *reinterpret_cast<float4*>(lb1 + r * 16 + cs * 4) = pb1[i];
    *reinterpret_cast<float4*>(lb3 + r * 16 + cs * 4) = pb3[i];
  }
  __syncthreads();
  int pr = r0 + (threadIdx.x >> 3);
  int fg = (threadIdx.x & 7) << 4;
  int tok = pair_tok[pr];
  if (tok < 0) return;
  const u16* bp = base13 + (size_t)tok * BCOLS;
  short8 x1a = *(const short8*)(bp + TWOF + e * 16);
  short8 x1b = *(const short8*)(bp + TWOF + e * 16 + 8);
  short8 x3a = *(const short8*)(bp + TWOF + NEXP * RLORA + e * 16);
  short8 x3b = *(const short8*)(bp + TWOF + NEXP * RLORA + e * 16 + 8);
  float xa1[16], xa3[16];
#pragma unroll
  for (int r = 0; r < 8; ++r) {
    xa1[r] = b2f(x1a[r]); xa1[r + 8] = b2f(x1b[r]);
    xa3[r] = b2f(x3a[r]); xa3[r + 8] = b2f(x3b[r]);
  }
  short8 h1a = *(const short8*)(bp + f0 + fg);
  short8 h1b = *(const short8*)(bp + f0 + fg + 8);
  short8 h3a = *(const short8*)(bp + FDIM + f0 + fg);
  short8 h3b = *(const short8*)(bp + FDIM + f0 + fg + 8);
  short8 o0, o1;
#pragma unroll
  for (int ii = 0; ii < 16; ++ii) {
    float hb1 = b2f(ii < 8 ? h1a[ii] : h1b[ii - 8]);
    float hb3 = b2f(ii < 8 ? h3a[ii] : h3b[ii - 8]);
    int row = fg + ii;
    int rot = row >> 5;
    const float* l1 = lb1 + row * 16;
    const float* l3 = lb3 + row * 16;
    float d1 = 0.f, d3 = 0.f;
#pragma unroll
    for (int c = 0; c < 4; ++c) {
      int cs = ((c + rot) & 3) << 2;
      float4 v1 = *reinterpret_cast<const float4*>(l1 + cs);
      float4 v3 = *reinterpret_cast<const float4*>(l3 + cs);
      d1 += xa1[4 * c + 0] * v1.x + xa1[4 * c + 1] * v1.y + xa1[4 * c + 2] * v1.z + xa1[4 * c + 3] * v1.w;
      d3 += xa3[4 * c + 0] * v3.x + xa3[4 * c + 1] * v3.y + xa3[4 * c + 2] * v3.z + xa3[4 * c + 3] * v3.w;
    }
    float h1 = hb1 + LSCALE * d1;
    float h3 = hb3 + LSCALE * d3;
    float s = h1 / (1.f + __expf(-h1));
    u16 ob = f2b(s * h3);
    if (ii < 8) o0[ii] = (short)ob; else o1[ii - 8] = (short)ob;
  }
  short8* dst = (short8*)(act + (size_t)pr * FDIM + f0 + fg);
  dst[0] = o0;
  dst[1] = o1;
}

// ------- ya2 = act @ a2b[e]^T via MFMA: 64-row x 16-col tiles, F-split x2 -------
// a2 pre-cast to bf16. Same verified stage/read swizzle geometry as mm128. Each
// block: 44 K-steps of 64, 4 waves (wave w = rows w*16..), acc f32x4/wave,
// fp32 atomicAdd merges the 2 F-halves into zeroed ya2. BW-bound (~143 MB total).
__global__ __launch_bounds__(256) void ya2_kernel(const u16* __restrict__ act, const u16* __restrict__ a2b,
                                                  const int* __restrict__ poff, float* __restrict__ ya2) {
  __shared__ char lA[8192];   // 64 rows x 64 k bf16
  __shared__ char lB[2048];   // 16 rows x 64 k bf16
  int m0 = blockIdx.x * 64;
  if (m0 >= poff[NEXP]) return;
  int e = 0;
  while (m0 >= poff[e + 1]) ++e;   // expert pads are 256-granular: 64-tile never spans
  int f0 = blockIdx.y * (FDIM / 2);
  const int tid = threadIdx.x;
  const int lane = tid & 63, w = tid >> 6;
  const int lm = lane & 15, lg = lane >> 4;
  const int col0 = (lg << 4) ^ ((lm & 7) << 4);
  const int rowAb = (w * 16 + lm) * 128;
  const int rowBb = lm * 128;
  const int lq = (lane >> 4) << 2;
  const u16* A = act + (size_t)m0 * FDIM + f0;
  const u16* B = a2b + (size_t)e * RLORA * FDIM + f0;
  f32x4 acc = {0.f, 0.f, 0.f, 0.f};
  for (int t = 0; t < FDIM / 128; ++t) {   // 44 K-steps per F-half
    __syncthreads();
#pragma unroll
    for (int h = 0; h < 2; ++h) {          // A: 512 chunks, 2/thread
      int q = h * 256 + tid, r = q >> 3, g = q & 7, gs = g ^ (r & 7);
      const char* s = (const char*)(A + (size_t)t * 64 + (size_t)r * FDIM) + gs * 16;
      __builtin_amdgcn_global_load_lds((const AS1 void*)s, (AS3 void*)(lA + q * 16), 16, 0, 0);
    }
    if (tid < 128) {                       // B: 128 chunks (waves 0-1, wave-uniform)
      int q = tid, r = q >> 3, g = q & 7, gs = g ^ (r & 7);
      const char* s = (const char*)(B + (size_t)t * 64 + (size_t)r * FDIM) + gs * 16;
      __builtin_amdgcn_global_load_lds((const AS1 void*)s, (AS3 void*)(lB + q * 16), 16, 0, 0);
    }
    __syncthreads();
#pragma unroll
    for (int kh = 0; kh < 2; ++kh) {
      int col = col0 ^ (kh << 6);
      short8 av = *(const short8*)(lA + rowAb + col);
      short8 bv = *(const short8*)(lB + rowBb + col);
      acc = __builtin_amdgcn_mfma_f32_16x16x32_bf16(av, bv, acc, 0, 0, 0);
    }
  }
#pragma unroll
  for (int q = 0; q < 4; ++q)
    atomicAdd(&ya2[(size_t)(m0 + w * 16 + lq + q) * RLORA + lm], acc[q]);
}

// -------- grouped down GEMM, tile-per-block + LoRA epilogue (r11 config) --------
__global__ __launch_bounds__(256, 4) void gemm_down(const u16* __restrict__ act, const u16* __restrict__ w2b,
                                                    const float* __restrict__ b2, const float* __restrict__ ya2,
                                                    const int* __restrict__ pair_tok, const int* __restrict__ pair_k,
                                                    const int* __restrict__ poff,
                                                    float* __restrict__ slots) {
  int orig = blockIdx.x;
  int wgid = (orig & 7) * 160 + (orig >> 3);
  int nt = wgid & 15;
  int miL = wgid >> 4;                        // 0..79
  int mi = ((miL % 10) << 3) + (miL / 10);    // bijective interleave on 0..79
  int m0 = mi << 7;
  if (m0 >= poff[NEXP]) return;
  int e = 0;
  while (m0 >= poff[e + 1]) ++e;              // 256-granular padding: tile within one expert
  int n0 = nt << 7;
  __shared__ char lA[16384];
  __shared__ char lB[16384];
  const int tid = threadIdx.x;
  const int lane = tid & 63, wid = tid >> 6;
  const int wr = wid >> 1, wc = wid & 1;
  const int lm = lane & 15, lg = lane >> 4;
  const int col0 = (lg << 4) ^ ((lm & 7) << 4);
  const int rowAb = (wr * 64 + lm) * 128;
  const int rowBb = (wc * 64 + lm) * 128;
  const int lq = (lane >> 4) << 2;
  f32x4 acc[4][4];
  f32x4 z = {0.f, 0.f, 0.f, 0.f};
#pragma unroll
  for (int i = 0; i < 4; ++i)
#pragma unroll
    for (int j = 0; j < 4; ++j) acc[i][j] = z;
  mm128(act + (size_t)m0 * FDIM, w2b + (size_t)n0 * FDIM, FDIM, FDIM, FDIM / 64,
        lA, lB, tid, rowAb, rowBb, col0, acc);
#pragma unroll
  for (int n = 0; n < 4; ++n) {
    int col = n0 + wc * 64 + n * 16 + lm;
    const float* b2p = b2 + ((size_t)e * DDIM + col) * RLORA;
    float b2v[16];
#pragma unroll
    for (int rr = 0; rr < 16; ++rr) b2v[rr] = b2p[rr];
#pragma unroll
    for (int i = 0; i < 4; ++i) {
#pragma unroll
      for (int q = 0; q < 4; ++q) {
        int pidx = m0 + wr * 64 + i * 16 + lq + q;
        int tok = pair_tok[pidx];
        if (tok < 0) continue;
        const float* yr = ya2 + (size_t)pidx * RLORA;
        float dot = 0.f;
#pragma unroll
        for (int rr = 0; rr < 16; ++rr) dot += yr[rr] * b2v[rr];
        slots[((size_t)tok * 2 + pair_k[pidx]) * DDIM + col] = acc[i][n][q] + LSCALE * dot;
      }
    }
  }
}

// ---------------- combine: out = w0*slot0 + w1*slot1 ----------------
__global__ __launch_bounds__(256) void combine_kernel(const float4* __restrict__ slots,
                                                      const float2* __restrict__ tok_w,
                                                      float4* __restrict__ out) {
  const int n4 = NTOK * (DDIM / 4);
  int stride = gridDim.x * 256;
  for (int i = blockIdx.x * 256 + threadIdx.x; i < n4; i += stride) {
    int tok = i >> 9;          // DDIM/4 = 512
    int c = i & 511;
    float2 w = tok_w[tok];
    float4 v0 = slots[(size_t)(tok * 2) * 512 + c];
    float4 v1 = slots[(size_t)(tok * 2 + 1) * 512 + c];
    float4 o;
    o.x = w.x * v0.x + w.y * v1.x;
    o.y = w.x * v0.y + w.y * v1.y;
    o.z = w.x * v0.z + w.y * v1.z;
    o.w = w.x * v0.w + w.y * v1.w;
    out[i] = o;
  }
}

extern "C" void kernel_launch(void* const* d_in, const int* in_sizes, int n_in,
                              void* d_out, int out_size, void* d_ws, size_t ws_size,
                              hipStream_t stream) {
  (void)in_sizes; (void)n_in; (void)out_size; (void)ws_size;
  const float* x  = (const float*)d_in[0];
  const float* gw = (const float*)d_in[1];
  const float* w1 = (const float*)d_in[2];
  const float* w3 = (const float*)d_in[3];
  const float* w2 = (const float*)d_in[4];
  const float* a1 = (const float*)d_in[5];
  const float* b1 = (const float*)d_in[6];
  const float* a3 = (const float*)d_in[7];
  const float* b3 = (const float*)d_in[8];
  const float* a2 = (const float*)d_in[9];
  const float* b2 = (const float*)d_in[10];
  float* out = (float*)d_out;

  char* ws = (char*)d_ws;
  size_t off = 0;
  auto take = [&](size_t bytes) -> char* {
    char* p = ws + off;
    off += (bytes + 255) & ~(size_t)255;
    return p;
  };
  // region 1: base13 (94.4 MB) -> later reused by slots (67.1 MB)
  char* reg1 = take((size_t)NTOK * BCOLS * 2);
  u16* base13 = (u16*)reg1;
  float* slots = (float*)reg1;
  // region 2: act (115.3 MB); xb (16.8) + Ball (47.2) overlap its head (dead after gemm_base)
  char* reg2 = take((size_t)PADROWS * FDIM * 2);
  u16* actb = (u16*)reg2;
  u16* xb = (u16*)reg2;
  u16* Ball = (u16*)(reg2 + (size_t)NTOK * DDIM * 2);
  // region 3: w2b + a2b + ya2 + small arrays (ya2 NOT aliased: live alongside slots)
  u16* w2b = (u16*)take((size_t)DDIM * FDIM * 2);
  u16* a2b = (u16*)take((size_t)NEXP * RLORA * FDIM * 2);
  float* ya2 = (float*)take((size_t)PADROWS * RLORA * 4);
  int2* tok_e   = (int2*)take((size_t)NTOK * 8);
  float2* tok_w = (float2*)take((size_t)NTOK * 8);
  int* pair_tok = (int*)take((size_t)PADROWS * 4);
  int* pair_k   = (int*)take((size_t)PADROWS * 4);
  int* poff     = (int*)take(256);

  cast_ball<<<2048, 256, 0, stream>>>(w1, w3, a1, a3, Ball);
  cast_kernel<<<1024, 256, 0, stream>>>(w2, w2b, DDIM * FDIM / 4);
  cast_kernel<<<64, 256, 0, stream>>>(a2, a2b, NEXP * RLORA * FDIM / 4);
  router_cast<<<NTOK, 256, 0, stream>>>(x, gw, tok_e, tok_w, xb);
  build_pairs<<<1, 256, 0, stream>>>(tok_e, pair_tok, pair_k, poff);
  gemm_base<<<2880, 256, 0, stream>>>(xb, Ball, base13);
  dim3 g3(FDIM / 128, PADROWS / 32);
  act_kernel<<<g3, 256, 0, stream>>>(base13, b1, b3, pair_tok, poff, actb);
  hipMemsetAsync(ya2, 0, (size_t)PADROWS * RLORA * 4, stream);
  dim3 gy(PADROWS / 64, 2);
  ya2_kernel<<<gy, 256, 0, stream>>>(actb, a2b, poff, ya2);
  gemm_down<<<1280, 256, 0, stream>>>(actb, w2b, b2, ya2, pair_tok, pair_k, poff, slots);
  combine_kernel<<<2048, 256, 0, stream>>>((const float4*)slots, tok_w, (float4*)out);
}